// Round 8
// baseline (377.502 us; speedup 1.0000x reference)
//
#include <hip/hip_runtime.h>
#include <hip/hip_bf16.h>
#include <stdint.h>

// Problem constants: B=16, S=1024, D=768, H=12, HD=64
// log2(e)/sqrt(64) folded into stored q so softmax runs in exp2 domain.
#define QSCALE 0.1803368801111204f

typedef unsigned short u16;
typedef __attribute__((ext_vector_type(8))) short short8;   // 8 bf16 = 4 VGPR
typedef __attribute__((ext_vector_type(4))) float f32x4;    // MFMA 16x16 acc

__device__ __forceinline__ u16 f2bf(float f) {  // RNE f32->bf16
  uint32_t x = __builtin_bit_cast(uint32_t, f);
  x += 0x7fffu + ((x >> 16) & 1u);
  return (u16)(x >> 16);
}

__device__ __forceinline__ uint32_t cvtpk(float lo, float hi) {
  uint32_t r;
  asm("v_cvt_pk_bf16_f32 %0, %1, %2" : "=v"(r) : "v"(lo), "v"(hi));
  return r;
}

__device__ __forceinline__ void async16(const void* g, void* l) {
  __builtin_amdgcn_global_load_lds(
      (const __attribute__((address_space(1))) uint32_t*)g,
      (__attribute__((address_space(3))) uint32_t*)l, 16, 0, 0);
}

// ---------------------------------------------------------------- converts
__global__ void __launch_bounds__(256) k_convert_x(const float* __restrict__ x,
                                                   u16* __restrict__ xb) {
  const int n4 = (16 * 1024 * 768) / 4;
  int i = blockIdx.x * 256 + threadIdx.x;
  const int stride = gridDim.x * 256;
  for (; i < n4; i += stride) {
    float4 v = ((const float4*)x)[i];
    uint2 u;
    u.x = cvtpk(v.x, v.y);
    u.y = cvtpk(v.z, v.w);
    ((uint2*)xb)[i] = u;
  }
}

// wqkvT[n][d] = W{q,k,v}[d][n%768]  (n = proj*768 + h*64 + e), bf16
// woT[e][hhd] = Wo[hhd][e], bf16
__global__ void __launch_bounds__(256) k_convert_w(
    const float* __restrict__ Wq, const float* __restrict__ Wk,
    const float* __restrict__ Wv, const float* __restrict__ Wo,
    u16* __restrict__ wqkvT, u16* __restrict__ woT) {
  int idx = blockIdx.x * 256 + threadIdx.x;  // 9216*256 == 2359296 exact
  if (idx < 2304 * 768) {
    int nrow = idx / 768;
    int d = idx - nrow * 768;
    int proj = nrow / 768;
    int rem = nrow - proj * 768;
    const float* W = (proj == 0) ? Wq : ((proj == 1) ? Wk : Wv);
    wqkvT[idx] = f2bf(W[d * 768 + rem]);
  } else {
    int j = idx - 2304 * 768;
    int e = j / 768;
    int hhd = j - e * 768;
    woT[j] = f2bf(Wo[hhd * 768 + e]);
  }
}

// ---------------------------------------------------------------- GEMM core
// 128x128 tile, BK=32, 4 waves 2x2 — upgraded to the T3 minimum 2-phase:
// double-buffered LDS, STAGE(t+1) issued before compute(t), ONE barrier per
// K-step (drains next-tile vmcnt + protects cur buffer reuse).
// 2-bit both-sides XOR swizzle (slot ^= row&3) on 64-B LDS rows cuts the
// ds_read_b128 bank conflict 8-way -> 4-way (rule #21: inverse-swizzled
// global source + swizzled read; involution).
// A: [M][768] bf16 row-major; B: [N][768] bf16 row-major (B^T input).
__device__ __forceinline__ void gemm_tile_k768(const u16* __restrict__ Atile,
                                               const u16* __restrict__ Btile,
                                               u16* As, u16* Bs,  // [2][4096] each
                                               f32x4 acc[4][4]) {
  const int tid = threadIdx.x;
  const int lane = tid & 63, w = tid >> 6;
  const int wr = w >> 1, wc = w & 1;
  const int g = lane >> 4, cr = lane & 15;
  const int q0 = tid, q1 = tid + 256;
  // inverse-swizzled global source: physical slot p holds logical slot p^(row&3)
  const size_t ga0 = (size_t)(q0 >> 2) * 1536 +
                     (size_t)((((q0 & 3) ^ ((q0 >> 2) & 3)) * 16));
  const size_t ga1 = (size_t)(q1 >> 2) * 1536 +
                     (size_t)((((q1 & 3) ^ ((q1 >> 2) & 3)) * 16));

#define GSTAGE(buf, kt)                                                       \
  do {                                                                        \
    const char* Ag = (const char*)Atile + (kt)*64;                            \
    const char* Bg = (const char*)Btile + (kt)*64;                            \
    async16(Ag + ga0, (char*)As + (buf)*8192 + q0 * 16);                      \
    async16(Ag + ga1, (char*)As + (buf)*8192 + q1 * 16);                      \
    async16(Bg + ga0, (char*)Bs + (buf)*8192 + q0 * 16);                      \
    async16(Bg + ga1, (char*)Bs + (buf)*8192 + q1 * 16);                      \
  } while (0)

  GSTAGE(0, 0);
  __syncthreads();  // drain prologue
  int cur = 0;
  for (int kt = 0; kt < 24; ++kt) {
    if (kt < 23) GSTAGE(cur ^ 1, kt + 1);  // next tile flies under compute
    const char* Ab = (const char*)As + cur * 8192;
    const char* Bb = (const char*)Bs + cur * 8192;
    short8 a[4], b[4];
#pragma unroll
    for (int i = 0; i < 4; ++i) {
      const int row = wr * 64 + i * 16 + cr;
      a[i] = *(const short8*)(Ab + row * 64 + ((g ^ (row & 3)) * 16));
    }
#pragma unroll
    for (int i = 0; i < 4; ++i) {
      const int row = wc * 64 + i * 16 + cr;
      b[i] = *(const short8*)(Bb + row * 64 + ((g ^ (row & 3)) * 16));
    }
#pragma unroll
    for (int mi = 0; mi < 4; ++mi)
#pragma unroll
      for (int ni = 0; ni < 4; ++ni)
        acc[mi][ni] = __builtin_amdgcn_mfma_f32_16x16x32_bf16(
            a[mi], b[ni], acc[mi][ni], 0, 0, 0);
    __syncthreads();  // drains next-tile loads + protects cur for overwrite
    cur ^= 1;
  }
#undef GSTAGE
}

// ------------------------------------------------------------- GEMM1: QKV
// 1-D grid 2304 = 8 XCD chunks x 288; within chunk y-minor (by = lb%18) so
// the 3.5MB weight set stays L2-resident and each A-panel is reused 18x.
__global__ void __launch_bounds__(256) k_gemm_qkv(
    const u16* __restrict__ xb, const u16* __restrict__ wT,
    const float* __restrict__ bq, const float* __restrict__ bk,
    const float* __restrict__ bv,
    u16* __restrict__ qbuf, u16* __restrict__ kbuf, u16* __restrict__ vbuf) {
  __shared__ __align__(16) u16 As[2 * 128 * 32];
  __shared__ __align__(16) u16 Bs[2 * 128 * 32];
  const int lb = (blockIdx.x & 7) * 288 + (blockIdx.x >> 3);
  const int bx = lb / 18, by = lb - bx * 18;

  f32x4 acc[4][4];
#pragma unroll
  for (int i = 0; i < 4; ++i)
#pragma unroll
    for (int j = 0; j < 4; ++j) acc[i][j] = (f32x4){0.f, 0.f, 0.f, 0.f};

  gemm_tile_k768(xb + (size_t)bx * 128 * 768,
                 wT + (size_t)by * 128 * 768, As, Bs, acc);

  const int lane = threadIdx.x & 63, w = threadIdx.x >> 6;
  const int wr = w >> 1, wc = w & 1, g = lane >> 4, cr = lane & 15;
  const int mbase = bx * 128 + wr * 64;
  const int nbase = by * 128 + wc * 64;
#pragma unroll
  for (int ni = 0; ni < 4; ++ni) {
    const int n = nbase + ni * 16 + cr;
    const int proj = n / 768;           // fragment never straddles (768%16==0)
    const int rem = n - proj * 768;     // h*64+e
    const int h = rem >> 6, e = rem & 63;
    const float bias = ((proj == 0) ? bq : (proj == 1) ? bk : bv)[rem];
#pragma unroll
    for (int mi = 0; mi < 4; ++mi) {
      const int mrow = mbase + mi * 16 + g * 4;
      const int b = mrow >> 10, s0 = mrow & 1023;
#pragma unroll
      for (int r = 0; r < 4; ++r) {
        const float val = acc[mi][ni][r] + bias;
        const int s = s0 + r;
        if (proj == 0) {
          qbuf[((size_t)(b * 12 + h) * 1024 + s) * 64 + e] = f2bf(val * QSCALE);
        } else if (proj == 1) {
          kbuf[((size_t)(b * 12 + h) * 1024 + s) * 64 + e] = f2bf(val);
        } else {
          vbuf[((size_t)(b * 12 + h) * 64 + e) * 1024 + s] = f2bf(val);
        }
      }
    }
  }
}

// --------------------------------------------------------------- attention
// 1 block = (b,h, 128 q rows); 4 waves x 32 q-rows. KV tiles of 64.
// Swapped QK^T (S^T = mfma(K,Q)): lane owns one q-column per half.
// T13 defer-max (THR=8, exp2 domain): skip O-rescale + alpha broadcasts
// unless the tile max exceeds running max by >8. P->bf16 via v_cvt_pk,
// written as ds_write_b64 pairs.
__global__ void __launch_bounds__(256) attn(const u16* __restrict__ qb,
                                            const u16* __restrict__ kb,
                                            const u16* __restrict__ vb,
                                            u16* __restrict__ ob) {
  __shared__ __align__(16) u16 Ks[2][64 * 64];
  __shared__ __align__(16) u16 Vs[2][64 * 64];
  __shared__ __align__(16) u16 Ps[4][32 * 64];  // per-wave P scratch

  // T1 chunked swizzle: launched i runs on XCD i%8; give each XCD 192
  // consecutive logical blocks = 24 complete (b,h) groups.
  const int lb = (blockIdx.x & 7) * 192 + (blockIdx.x >> 3);
  const int bh = lb >> 3, qi = lb & 7;
  const int tid = threadIdx.x, lane = tid & 63, w = tid >> 6;
  const int g = lane >> 4, cr = lane & 15;

  const u16* qbase = qb + ((size_t)bh * 1024 + qi * 128 + w * 32) * 64;
  const char* kbase = (const char*)(kb + (size_t)bh * 1024 * 64);
  const char* vbase = (const char*)(vb + (size_t)bh * 1024 * 64);

  // Q fragments in registers (pre-scaled by log2e/8 at projection time)
  short8 qf[2][2];
#pragma unroll
  for (int m = 0; m < 2; ++m)
#pragma unroll
    for (int kk = 0; kk < 2; ++kk)
      qf[m][kk] = *(const short8*)(qbase + (m * 16 + cr) * 64 + kk * 32 + g * 8);

  f32x4 O[2][4];
  float mrun[2], lrun[2];
#pragma unroll
  for (int m = 0; m < 2; ++m) {
#pragma unroll
    for (int i = 0; i < 4; ++i) O[m][i] = (f32x4){0.f, 0.f, 0.f, 0.f};
    mrun[m] = -1e30f;
    lrun[m] = 0.f;
  }

  const int q0 = tid, q1 = tid + 256;
  const int r0 = q0 >> 3, sc0 = ((q0 & 7) * 16) ^ ((r0 & 7) << 4);
  const int r1 = q1 >> 3, sc1 = ((q1 & 7) * 16) ^ ((r1 & 7) << 4);
  char* Psw = (char*)&Ps[w][0];

#define STAGE(buf, t)                                                        \
  do {                                                                       \
    async16(kbase + (size_t)((t)*64 + r0) * 128 + sc0, (char*)Ks[buf] + q0 * 16); \
    async16(kbase + (size_t)((t)*64 + r1) * 128 + sc1, (char*)Ks[buf] + q1 * 16); \
    async16(vbase + (size_t)r0 * 2048 + (t)*128 + sc0, (char*)Vs[buf] + q0 * 16); \
    async16(vbase + (size_t)r1 * 2048 + (t)*128 + sc1, (char*)Vs[buf] + q1 * 16); \
  } while (0)

  STAGE(0, 0);
  __syncthreads();  // drain prologue loads
  int cur = 0;

  for (int t = 0; t < 16; ++t) {
    if (t < 15) STAGE(cur ^ 1, t + 1);  // issue next tile early (hides HBM)

    // ---- S^T = K * Q^T : C[row=kv_local][col=q_local]
    short8 kf[4][2];
#pragma unroll
    for (int n = 0; n < 4; ++n)
#pragma unroll
      for (int kk = 0; kk < 2; ++kk) {
        const int row = n * 16 + cr;
        kf[n][kk] = *(const short8*)((char*)Ks[cur] + row * 128 +
                                     ((kk * 64 + g * 16) ^ ((row & 7) << 4)));
      }
    f32x4 sT[4][2];  // [kv-frag n][q-half m]
#pragma unroll
    for (int n = 0; n < 4; ++n)
#pragma unroll
      for (int m = 0; m < 2; ++m) sT[n][m] = (f32x4){0.f, 0.f, 0.f, 0.f};
    __builtin_amdgcn_s_setprio(1);
#pragma unroll
    for (int n = 0; n < 4; ++n)
#pragma unroll
      for (int kk = 0; kk < 2; ++kk) {
        sT[n][0] = __builtin_amdgcn_mfma_f32_16x16x32_bf16(kf[n][kk], qf[0][kk], sT[n][0], 0, 0, 0);
        sT[n][1] = __builtin_amdgcn_mfma_f32_16x16x32_bf16(kf[n][kk], qf[1][kk], sT[n][1], 0, 0, 0);
      }
    __builtin_amdgcn_s_setprio(0);

    // ---- tile max per q-column (tree shape -> v_max3 fusable)
    float mx[2];
#pragma unroll
    for (int m = 0; m < 2; ++m) {
      float t0 = fmaxf(fmaxf(sT[0][m][0], sT[0][m][1]), fmaxf(sT[0][m][2], sT[0][m][3]));
      float t1 = fmaxf(fmaxf(sT[1][m][0], sT[1][m][1]), fmaxf(sT[1][m][2], sT[1][m][3]));
      float t2 = fmaxf(fmaxf(sT[2][m][0], sT[2][m][1]), fmaxf(sT[2][m][2], sT[2][m][3]));
      float t3 = fmaxf(fmaxf(sT[3][m][0], sT[3][m][1]), fmaxf(sT[3][m][2], sT[3][m][3]));
      float v = fmaxf(fmaxf(t0, t1), fmaxf(t2, t3));
      v = fmaxf(v, __shfl_xor(v, 16));
      v = fmaxf(v, __shfl_xor(v, 32));
      mx[m] = v;
    }

    // ---- T13 defer-max: rescale only when some column grew by > 8
    if (!__all(mx[0] <= mrun[0] + 8.f && mx[1] <= mrun[1] + 8.f)) {
      float al[2];
#pragma unroll
      for (int m = 0; m < 2; ++m) {
        const float mnew = fmaxf(mrun[m], mx[m]);
        al[m] = __builtin_amdgcn_exp2f(mrun[m] - mnew);
        mrun[m] = mnew;
        lrun[m] *= al[m];
      }
#pragma unroll
      for (int m = 0; m < 2; ++m)
#pragma unroll
        for (int r = 0; r < 4; ++r) {
          const float aO = __shfl(al[m], (g << 4) + g * 4 + r, 64);
#pragma unroll
          for (int nn = 0; nn < 4; ++nn) O[m][nn][r] *= aO;
        }
    }

    // ---- P = exp2(S - m), row-sum, pack to bf16, write b64 to Ps
#pragma unroll
    for (int m = 0; m < 2; ++m) {
      const float mm = mrun[m];
      float rs = 0.f;
      const int q = m * 16 + cr;
      const int swz = (q & 7) << 4;
      char* prow = Psw + q * 128;
#pragma unroll
      for (int n = 0; n < 4; ++n) {
        float p0 = __builtin_amdgcn_exp2f(sT[n][m][0] - mm);
        float p1 = __builtin_amdgcn_exp2f(sT[n][m][1] - mm);
        float p2 = __builtin_amdgcn_exp2f(sT[n][m][2] - mm);
        float p3 = __builtin_amdgcn_exp2f(sT[n][m][3] - mm);
        rs += (p0 + p1) + (p2 + p3);
        uint2 pw;
        pw.x = cvtpk(p0, p1);
        pw.y = cvtpk(p2, p3);
        *(uint2*)(prow + ((n * 32 + g * 8) ^ swz)) = pw;
      }
      rs += __shfl_xor(rs, 16);
      rs += __shfl_xor(rs, 32);
      lrun[m] += rs;
    }

    // ---- O += P * V : A=P (rows=q), B=V (cols=hd) -> C[row=q][col=hd]
    short8 pf[2][2];
#pragma unroll
    for (int m = 0; m < 2; ++m)
#pragma unroll
      for (int kk = 0; kk < 2; ++kk) {
        const int q = m * 16 + cr;
        pf[m][kk] = *(const short8*)(Psw + q * 128 +
                                     ((kk * 64 + g * 16) ^ ((q & 7) << 4)));
      }
    short8 vf[4][2];
#pragma unroll
    for (int nn = 0; nn < 4; ++nn)
#pragma unroll
      for (int kk = 0; kk < 2; ++kk) {
        const int row = nn * 16 + cr;
        vf[nn][kk] = *(const short8*)((char*)Vs[cur] + row * 128 +
                                      ((kk * 64 + g * 16) ^ ((row & 7) << 4)));
      }
    __builtin_amdgcn_s_setprio(1);
#pragma unroll
    for (int nn = 0; nn < 4; ++nn)
#pragma unroll
      for (int kk = 0; kk < 2; ++kk) {
        O[0][nn] = __builtin_amdgcn_mfma_f32_16x16x32_bf16(pf[0][kk], vf[nn][kk], O[0][nn], 0, 0, 0);
        O[1][nn] = __builtin_amdgcn_mfma_f32_16x16x32_bf16(pf[1][kk], vf[nn][kk], O[1][nn], 0, 0, 0);
      }
    __builtin_amdgcn_s_setprio(0);

    __syncthreads();  // drain next-tile loads + protect Ks/Vs reuse
    cur ^= 1;
  }
#undef STAGE

  // epilogue: o[b][s][h*64+hd] bf16; row q = m*16+g*4+r, col hd = nn*16+cr
  const int b = bh / 12, h = bh - b * 12;
#pragma unroll
  for (int m = 0; m < 2; ++m)
#pragma unroll
    for (int r = 0; r < 4; ++r) {
      const float l = __shfl(lrun[m], (g << 4) + g * 4 + r, 64);
      const float inv = 1.0f / l;
      const int s = qi * 128 + w * 32 + m * 16 + g * 4 + r;
      const size_t rowoff = (size_t)(b * 1024 + s) * 768 + h * 64;
#pragma unroll
      for (int nn = 0; nn < 4; ++nn)
        ob[rowoff + nn * 16 + cr] = f2bf(O[m][nn][r] * inv);
    }
}

// ------------------------------------------------------------ GEMM2: out
// 1-D grid 768 = 8 XCD chunks x 96; y-minor (by = lb%6).
__global__ void __launch_bounds__(256) k_gemm_out(
    const u16* __restrict__ obuf, const u16* __restrict__ woT,
    const float* __restrict__ bo, float* __restrict__ out) {
  __shared__ __align__(16) u16 As[2 * 128 * 32];
  __shared__ __align__(16) u16 Bs[2 * 128 * 32];
  const int lb = (blockIdx.x & 7) * 96 + (blockIdx.x >> 3);
  const int bx = lb / 6, by = lb - bx * 6;

  f32x4 acc[4][4];
#pragma unroll
  for (int i = 0; i < 4; ++i)
#pragma unroll
    for (int j = 0; j < 4; ++j) acc[i][j] = (f32x4){0.f, 0.f, 0.f, 0.f};

  gemm_tile_k768(obuf + (size_t)bx * 128 * 768,
                 woT + (size_t)by * 128 * 768, As, Bs, acc);

  const int lane = threadIdx.x & 63, w = threadIdx.x >> 6;
  const int wr = w >> 1, wc = w & 1, g = lane >> 4, cr = lane & 15;
  const int mbase = bx * 128 + wr * 64;
  const int nbase = by * 128 + wc * 64;
#pragma unroll
  for (int ni = 0; ni < 4; ++ni) {
    const int n = nbase + ni * 16 + cr;
    const float bias = bo[n];
#pragma unroll
    for (int mi = 0; mi < 4; ++mi) {
      const int mrow = mbase + mi * 16 + g * 4;
#pragma unroll
      for (int r = 0; r < 4; ++r)
        out[(size_t)(mrow + r) * 768 + n] = acc[mi][ni][r] + bias;
    }
  }
}

// ---------------------------------------------------------------- launch
extern "C" void kernel_launch(void* const* d_in, const int* in_sizes, int n_in,
                              void* d_out, int out_size, void* d_ws, size_t ws_size,
                              hipStream_t stream) {
  const float* x  = (const float*)d_in[0];
  const float* Wq = (const float*)d_in[1];
  const float* bq = (const float*)d_in[2];
  const float* Wk = (const float*)d_in[3];
  const float* bk = (const float*)d_in[4];
  const float* Wv = (const float*)d_in[5];
  const float* bv = (const float*)d_in[6];
  const float* Wo = (const float*)d_in[7];
  const float* bo = (const float*)d_in[8];
  float* out = (float*)d_out;

  char* ws = (char*)d_ws;
  u16* xb    = (u16*)(ws);                  // 16384x768 bf16      = 25165824 B
  u16* wqkvT = (u16*)(ws + 25165824);       // 2304x768            =  3538944 B
  u16* woT   = (u16*)(ws + 28704768);       // 768x768             =  1179648 B
  u16* qbuf  = (u16*)(ws + 29884416);       // [B,H,S,HD]          = 25165824 B
  u16* kbuf  = (u16*)(ws + 55050240);       // [B,H,S,HD]          = 25165824 B
  u16* vbuf  = (u16*)(ws + 80216064);       // [B,H,HD,S]          = 25165824 B
  u16* obuf  = (u16*)(ws + 105381888);      // [B,S,H*HD]          = 25165824 B
                                            // total 130547712 B

  k_convert_x<<<4096, 256, 0, stream>>>(x, xb);
  k_convert_w<<<9216, 256, 0, stream>>>(Wq, Wk, Wv, Wo, wqkvT, woT);
  k_gemm_qkv<<<2304, 256, 0, stream>>>(xb, wqkvT, bq, bk, bv,
                                       qbuf, kbuf, vbuf);
  attn<<<1536, 256, 0, stream>>>(qbuf, kbuf, vbuf, obuf);
  k_gemm_out<<<768, 256, 0, stream>>>(obuf, woT, bo, out);
}

// Round 11
// 369.194 us; speedup vs baseline: 1.0225x; 1.0225x over previous
//
#include <hip/hip_runtime.h>
#include <hip/hip_bf16.h>
#include <stdint.h>

// Problem constants: B=16, S=1024, D=768, H=12, HD=64
// log2(e)/sqrt(64) folded into stored q so softmax runs in exp2 domain.
#define QSCALE 0.1803368801111204f

typedef unsigned short u16;
typedef __attribute__((ext_vector_type(8))) short short8;   // 8 bf16 = 4 VGPR
typedef __attribute__((ext_vector_type(4))) float f32x4;    // MFMA 16x16 acc

__device__ __forceinline__ u16 f2bf(float f) {  // RNE f32->bf16
  uint32_t x = __builtin_bit_cast(uint32_t, f);
  x += 0x7fffu + ((x >> 16) & 1u);
  return (u16)(x >> 16);
}

__device__ __forceinline__ uint32_t cvtpk(float lo, float hi) {
  uint32_t r;
  asm("v_cvt_pk_bf16_f32 %0, %1, %2" : "=v"(r) : "v"(lo), "v"(hi));
  return r;
}

__device__ __forceinline__ void async16(const void* g, void* l) {
  __builtin_amdgcn_global_load_lds(
      (const __attribute__((address_space(1))) uint32_t*)g,
      (__attribute__((address_space(3))) uint32_t*)l, 16, 0, 0);
}

// ---------------------------------------------------------------- converts
__global__ void __launch_bounds__(256) k_convert_x(const float* __restrict__ x,
                                                   u16* __restrict__ xb) {
  const int n4 = (16 * 1024 * 768) / 4;
  int i = blockIdx.x * 256 + threadIdx.x;
  const int stride = gridDim.x * 256;
  for (; i < n4; i += stride) {
    float4 v = ((const float4*)x)[i];
    uint2 u;
    u.x = cvtpk(v.x, v.y);
    u.y = cvtpk(v.z, v.w);
    ((uint2*)xb)[i] = u;
  }
}

// wqkvT[n][d] = W{q,k,v}[d][n%768]  (n = proj*768 + h*64 + e), bf16
// woT[e][hhd] = Wo[hhd][e], bf16
__global__ void __launch_bounds__(256) k_convert_w(
    const float* __restrict__ Wq, const float* __restrict__ Wk,
    const float* __restrict__ Wv, const float* __restrict__ Wo,
    u16* __restrict__ wqkvT, u16* __restrict__ woT) {
  int idx = blockIdx.x * 256 + threadIdx.x;  // 9216*256 == 2359296 exact
  if (idx < 2304 * 768) {
    int nrow = idx / 768;
    int d = idx - nrow * 768;
    int proj = nrow / 768;
    int rem = nrow - proj * 768;
    const float* W = (proj == 0) ? Wq : ((proj == 1) ? Wk : Wv);
    wqkvT[idx] = f2bf(W[d * 768 + rem]);
  } else {
    int j = idx - 2304 * 768;
    int e = j / 768;
    int hhd = j - e * 768;
    woT[j] = f2bf(Wo[hhd * 768 + e]);
  }
}

// ---------------------------------------------------------------- GEMM core
// 128x128 tile, BK=32, 4 waves 2x2. T4 counted-vmcnt 2-phase (m218 lever):
// per K-step { GSTAGE(next); s_waitcnt vmcnt(4); s_barrier; ds_read; MFMA;
// s_barrier } — the 4 prefetch loads stay in flight across BOTH barriers
// (never drained to 0 in the loop). Unrolled x2 so buffer indices are
// compile-time constants (addresses hoist; rule #20). Linear LDS layout
// (round-8 swizzle reverted: reads are uniform-bank, not conflicted).
__device__ __forceinline__ void gemm_tile_k768(const u16* __restrict__ Atile,
                                               const u16* __restrict__ Btile,
                                               u16* As, u16* Bs,  // [2][4096] each
                                               f32x4 acc[4][4]) {
  const int tid = threadIdx.x;
  const int lane = tid & 63, w = tid >> 6;
  const int wr = w >> 1, wc = w & 1;
  const int g = lane >> 4, cr = lane & 15;
  const int q0 = tid, q1 = tid + 256;
  const size_t ga0 = (size_t)(q0 >> 2) * 1536 + (size_t)((q0 & 3) * 16);
  const size_t ga1 = (size_t)(q1 >> 2) * 1536 + (size_t)((q1 & 3) * 16);
  const u16* aP = As + (wr * 64 + cr) * 32 + g * 8;  // row stride 32 u16
  const u16* bP = Bs + (wc * 64 + cr) * 32 + g * 8;

#define GSTAGE(buf, kt)                                                       \
  do {                                                                        \
    const char* Ag = (const char*)Atile + (kt)*64;                            \
    const char* Bg = (const char*)Btile + (kt)*64;                            \
    async16(Ag + ga0, (char*)As + (buf)*8192 + q0 * 16);                      \
    async16(Ag + ga1, (char*)As + (buf)*8192 + q1 * 16);                      \
    async16(Bg + ga0, (char*)Bs + (buf)*8192 + q0 * 16);                      \
    async16(Bg + ga1, (char*)Bs + (buf)*8192 + q1 * 16);                      \
  } while (0)

#define COMPUTE(buf)                                                          \
  do {                                                                        \
    short8 a[4], b[4];                                                        \
    _Pragma("unroll") for (int i = 0; i < 4; ++i)                             \
        a[i] = *(const short8*)(aP + (buf)*4096 + i * 512);                   \
    _Pragma("unroll") for (int i = 0; i < 4; ++i)                             \
        b[i] = *(const short8*)(bP + (buf)*4096 + i * 512);                   \
    __builtin_amdgcn_s_setprio(1);                                            \
    _Pragma("unroll") for (int mi = 0; mi < 4; ++mi)                          \
        _Pragma("unroll") for (int ni = 0; ni < 4; ++ni)                      \
            acc[mi][ni] = __builtin_amdgcn_mfma_f32_16x16x32_bf16(            \
                a[mi], b[ni], acc[mi][ni], 0, 0, 0);                          \
    __builtin_amdgcn_s_setprio(0);                                            \
  } while (0)

  GSTAGE(0, 0);
  for (int i = 0; i < 12; ++i) {
    GSTAGE(1, 2 * i + 1);
    asm volatile("s_waitcnt vmcnt(4)" ::: "memory");  // tile 2i landed
    __builtin_amdgcn_s_barrier();
    COMPUTE(0);
    __builtin_amdgcn_s_barrier();                     // buf0 reads done
    if (i < 11) {
      GSTAGE(0, 2 * i + 2);
      asm volatile("s_waitcnt vmcnt(4)" ::: "memory");  // tile 2i+1 landed
    } else {
      asm volatile("s_waitcnt vmcnt(0)" ::: "memory");  // last tile
    }
    __builtin_amdgcn_s_barrier();
    COMPUTE(1);
    __builtin_amdgcn_s_barrier();                     // buf1 reads done
  }
#undef GSTAGE
#undef COMPUTE
}

// ------------------------------------------------------------- GEMM1: QKV
// 1-D grid 2304 = 8 XCD chunks x 288; within chunk y-minor (by = lb%18) so
// the 3.5MB weight set stays L2-resident and each A-panel is reused 18x.
__global__ void __launch_bounds__(256) k_gemm_qkv(
    const u16* __restrict__ xb, const u16* __restrict__ wT,
    const float* __restrict__ bq, const float* __restrict__ bk,
    const float* __restrict__ bv,
    u16* __restrict__ qbuf, u16* __restrict__ kbuf, u16* __restrict__ vbuf) {
  __shared__ __align__(16) u16 As[2 * 128 * 32];
  __shared__ __align__(16) u16 Bs[2 * 128 * 32];
  const int lb = (blockIdx.x & 7) * 288 + (blockIdx.x >> 3);
  const int bx = lb / 18, by = lb - bx * 18;

  f32x4 acc[4][4];
#pragma unroll
  for (int i = 0; i < 4; ++i)
#pragma unroll
    for (int j = 0; j < 4; ++j) acc[i][j] = (f32x4){0.f, 0.f, 0.f, 0.f};

  gemm_tile_k768(xb + (size_t)bx * 128 * 768,
                 wT + (size_t)by * 128 * 768, As, Bs, acc);

  const int lane = threadIdx.x & 63, w = threadIdx.x >> 6;
  const int wr = w >> 1, wc = w & 1, g = lane >> 4, cr = lane & 15;
  const int mbase = bx * 128 + wr * 64;
  const int nbase = by * 128 + wc * 64;
#pragma unroll
  for (int ni = 0; ni < 4; ++ni) {
    const int n = nbase + ni * 16 + cr;
    const int proj = n / 768;           // fragment never straddles (768%16==0)
    const int rem = n - proj * 768;     // h*64+e
    const int h = rem >> 6, e = rem & 63;
    const float bias = ((proj == 0) ? bq : (proj == 1) ? bk : bv)[rem];
#pragma unroll
    for (int mi = 0; mi < 4; ++mi) {
      const int mrow = mbase + mi * 16 + g * 4;
      const int b = mrow >> 10, s0 = mrow & 1023;
#pragma unroll
      for (int r = 0; r < 4; ++r) {
        const float val = acc[mi][ni][r] + bias;
        const int s = s0 + r;
        if (proj == 0) {
          qbuf[((size_t)(b * 12 + h) * 1024 + s) * 64 + e] = f2bf(val * QSCALE);
        } else if (proj == 1) {
          kbuf[((size_t)(b * 12 + h) * 1024 + s) * 64 + e] = f2bf(val);
        } else {
          vbuf[((size_t)(b * 12 + h) * 64 + e) * 1024 + s] = f2bf(val);
        }
      }
    }
  }
}

// --------------------------------------------------------------- attention
// 1 block = (b,h, 128 q rows); 4 waves x 32 q-rows. KV tiles of 64.
// Swapped QK^T (S^T = mfma(K,Q)): lane owns one q-column per half.
// T13 defer-max (THR=8, exp2 domain): skip O-rescale + alpha broadcasts
// unless the tile max exceeds running max by >8. P->bf16 via v_cvt_pk,
// written as ds_write_b64 pairs.
__global__ void __launch_bounds__(256) attn(const u16* __restrict__ qb,
                                            const u16* __restrict__ kb,
                                            const u16* __restrict__ vb,
                                            u16* __restrict__ ob) {
  __shared__ __align__(16) u16 Ks[2][64 * 64];
  __shared__ __align__(16) u16 Vs[2][64 * 64];
  __shared__ __align__(16) u16 Ps[4][32 * 64];  // per-wave P scratch

  // T1 chunked swizzle: launched i runs on XCD i%8; give each XCD 192
  // consecutive logical blocks = 24 complete (b,h) groups.
  const int lb = (blockIdx.x & 7) * 192 + (blockIdx.x >> 3);
  const int bh = lb >> 3, qi = lb & 7;
  const int tid = threadIdx.x, lane = tid & 63, w = tid >> 6;
  const int g = lane >> 4, cr = lane & 15;

  const u16* qbase = qb + ((size_t)bh * 1024 + qi * 128 + w * 32) * 64;
  const char* kbase = (const char*)(kb + (size_t)bh * 1024 * 64);
  const char* vbase = (const char*)(vb + (size_t)bh * 1024 * 64);

  // Q fragments in registers (pre-scaled by log2e/8 at projection time)
  short8 qf[2][2];
#pragma unroll
  for (int m = 0; m < 2; ++m)
#pragma unroll
    for (int kk = 0; kk < 2; ++kk)
      qf[m][kk] = *(const short8*)(qbase + (m * 16 + cr) * 64 + kk * 32 + g * 8);

  f32x4 O[2][4];
  float mrun[2], lrun[2];
#pragma unroll
  for (int m = 0; m < 2; ++m) {
#pragma unroll
    for (int i = 0; i < 4; ++i) O[m][i] = (f32x4){0.f, 0.f, 0.f, 0.f};
    mrun[m] = -1e30f;
    lrun[m] = 0.f;
  }

  const int q0 = tid, q1 = tid + 256;
  const int r0 = q0 >> 3, sc0 = ((q0 & 7) * 16) ^ ((r0 & 7) << 4);
  const int r1 = q1 >> 3, sc1 = ((q1 & 7) * 16) ^ ((r1 & 7) << 4);
  char* Psw = (char*)&Ps[w][0];

#define STAGE(buf, t)                                                        \
  do {                                                                       \
    async16(kbase + (size_t)((t)*64 + r0) * 128 + sc0, (char*)Ks[buf] + q0 * 16); \
    async16(kbase + (size_t)((t)*64 + r1) * 128 + sc1, (char*)Ks[buf] + q1 * 16); \
    async16(vbase + (size_t)r0 * 2048 + (t)*128 + sc0, (char*)Vs[buf] + q0 * 16); \
    async16(vbase + (size_t)r1 * 2048 + (t)*128 + sc1, (char*)Vs[buf] + q1 * 16); \
  } while (0)

  STAGE(0, 0);
  __syncthreads();  // drain prologue loads
  int cur = 0;

  for (int t = 0; t < 16; ++t) {
    if (t < 15) STAGE(cur ^ 1, t + 1);  // issue next tile early (hides HBM)

    // ---- S^T = K * Q^T : C[row=kv_local][col=q_local]
    short8 kf[4][2];
#pragma unroll
    for (int n = 0; n < 4; ++n)
#pragma unroll
      for (int kk = 0; kk < 2; ++kk) {
        const int row = n * 16 + cr;
        kf[n][kk] = *(const short8*)((char*)Ks[cur] + row * 128 +
                                     ((kk * 64 + g * 16) ^ ((row & 7) << 4)));
      }
    f32x4 sT[4][2];  // [kv-frag n][q-half m]
#pragma unroll
    for (int n = 0; n < 4; ++n)
#pragma unroll
      for (int m = 0; m < 2; ++m) sT[n][m] = (f32x4){0.f, 0.f, 0.f, 0.f};
    __builtin_amdgcn_s_setprio(1);
#pragma unroll
    for (int n = 0; n < 4; ++n)
#pragma unroll
      for (int kk = 0; kk < 2; ++kk) {
        sT[n][0] = __builtin_amdgcn_mfma_f32_16x16x32_bf16(kf[n][kk], qf[0][kk], sT[n][0], 0, 0, 0);
        sT[n][1] = __builtin_amdgcn_mfma_f32_16x16x32_bf16(kf[n][kk], qf[1][kk], sT[n][1], 0, 0, 0);
      }
    __builtin_amdgcn_s_setprio(0);

    // ---- tile max per q-column (tree shape -> v_max3 fusable)
    float mx[2];
#pragma unroll
    for (int m = 0; m < 2; ++m) {
      float t0 = fmaxf(fmaxf(sT[0][m][0], sT[0][m][1]), fmaxf(sT[0][m][2], sT[0][m][3]));
      float t1 = fmaxf(fmaxf(sT[1][m][0], sT[1][m][1]), fmaxf(sT[1][m][2], sT[1][m][3]));
      float t2 = fmaxf(fmaxf(sT[2][m][0], sT[2][m][1]), fmaxf(sT[2][m][2], sT[2][m][3]));
      float t3 = fmaxf(fmaxf(sT[3][m][0], sT[3][m][1]), fmaxf(sT[3][m][2], sT[3][m][3]));
      float v = fmaxf(fmaxf(t0, t1), fmaxf(t2, t3));
      v = fmaxf(v, __shfl_xor(v, 16));
      v = fmaxf(v, __shfl_xor(v, 32));
      mx[m] = v;
    }

    // ---- T13 defer-max: rescale only when some column grew by > 8
    if (!__all(mx[0] <= mrun[0] + 8.f && mx[1] <= mrun[1] + 8.f)) {
      float al[2];
#pragma unroll
      for (int m = 0; m < 2; ++m) {
        const float mnew = fmaxf(mrun[m], mx[m]);
        al[m] = __builtin_amdgcn_exp2f(mrun[m] - mnew);
        mrun[m] = mnew;
        lrun[m] *= al[m];
      }
#pragma unroll
      for (int m = 0; m < 2; ++m)
#pragma unroll
        for (int r = 0; r < 4; ++r) {
          const float aO = __shfl(al[m], (g << 4) + g * 4 + r, 64);
#pragma unroll
          for (int nn = 0; nn < 4; ++nn) O[m][nn][r] *= aO;
        }
    }

    // ---- P = exp2(S - m), row-sum, pack to bf16, write b64 to Ps
#pragma unroll
    for (int m = 0; m < 2; ++m) {
      const float mm = mrun[m];
      float rs = 0.f;
      const int q = m * 16 + cr;
      const int swz = (q & 7) << 4;
      char* prow = Psw + q * 128;
#pragma unroll
      for (int n = 0; n < 4; ++n) {
        float p0 = __builtin_amdgcn_exp2f(sT[n][m][0] - mm);
        float p1 = __builtin_amdgcn_exp2f(sT[n][m][1] - mm);
        float p2 = __builtin_amdgcn_exp2f(sT[n][m][2] - mm);
        float p3 = __builtin_amdgcn_exp2f(sT[n][m][3] - mm);
        rs += (p0 + p1) + (p2 + p3);
        uint2 pw;
        pw.x = cvtpk(p0, p1);
        pw.y = cvtpk(p2, p3);
        *(uint2*)(prow + ((n * 32 + g * 8) ^ swz)) = pw;
      }
      rs += __shfl_xor(rs, 16);
      rs += __shfl_xor(rs, 32);
      lrun[m] += rs;
    }

    // ---- O += P * V : A=P (rows=q), B=V (cols=hd) -> C[row=q][col=hd]
    short8 pf[2][2];
#pragma unroll
    for (int m = 0; m < 2; ++m)
#pragma unroll
      for (int kk = 0; kk < 2; ++kk) {
        const int q = m * 16 + cr;
        pf[m][kk] = *(const short8*)(Psw + q * 128 +
                                     ((kk * 64 + g * 16) ^ ((q & 7) << 4)));
      }
    short8 vf[4][2];
#pragma unroll
    for (int nn = 0; nn < 4; ++nn)
#pragma unroll
      for (int kk = 0; kk < 2; ++kk) {
        const int row = nn * 16 + cr;
        vf[nn][kk] = *(const short8*)((char*)Vs[cur] + row * 128 +
                                      ((kk * 64 + g * 16) ^ ((row & 7) << 4)));
      }
    __builtin_amdgcn_s_setprio(1);
#pragma unroll
    for (int nn = 0; nn < 4; ++nn)
#pragma unroll
      for (int kk = 0; kk < 2; ++kk) {
        O[0][nn] = __builtin_amdgcn_mfma_f32_16x16x32_bf16(pf[0][kk], vf[nn][kk], O[0][nn], 0, 0, 0);
        O[1][nn] = __builtin_amdgcn_mfma_f32_16x16x32_bf16(pf[1][kk], vf[nn][kk], O[1][nn], 0, 0, 0);
      }
    __builtin_amdgcn_s_setprio(0);

    __syncthreads();  // drain next-tile loads + protect Ks/Vs reuse
    cur ^= 1;
  }
#undef STAGE

  // epilogue: o[b][s][h*64+hd] bf16; row q = m*16+g*4+r, col hd = nn*16+cr
  const int b = bh / 12, h = bh - b * 12;
#pragma unroll
  for (int m = 0; m < 2; ++m)
#pragma unroll
    for (int r = 0; r < 4; ++r) {
      const float l = __shfl(lrun[m], (g << 4) + g * 4 + r, 64);
      const float inv = 1.0f / l;
      const int s = qi * 128 + w * 32 + m * 16 + g * 4 + r;
      const size_t rowoff = (size_t)(b * 1024 + s) * 768 + h * 64;
#pragma unroll
      for (int nn = 0; nn < 4; ++nn)
        ob[rowoff + nn * 16 + cr] = f2bf(O[m][nn][r] * inv);
    }
}

// ------------------------------------------------------------ GEMM2: out
// 1-D grid 768 = 8 XCD chunks x 96; y-minor (by = lb%6).
__global__ void __launch_bounds__(256) k_gemm_out(
    const u16* __restrict__ obuf, const u16* __restrict__ woT,
    const float* __restrict__ bo, float* __restrict__ out) {
  __shared__ __align__(16) u16 As[2 * 128 * 32];
  __shared__ __align__(16) u16 Bs[2 * 128 * 32];
  const int lb = (blockIdx.x & 7) * 96 + (blockIdx.x >> 3);
  const int bx = lb / 6, by = lb - bx * 6;

  f32x4 acc[4][4];
#pragma unroll
  for (int i = 0; i < 4; ++i)
#pragma unroll
    for (int j = 0; j < 4; ++j) acc[i][j] = (f32x4){0.f, 0.f, 0.f, 0.f};

  gemm_tile_k768(obuf + (size_t)bx * 128 * 768,
                 woT + (size_t)by * 128 * 768, As, Bs, acc);

  const int lane = threadIdx.x & 63, w = threadIdx.x >> 6;
  const int wr = w >> 1, wc = w & 1, g = lane >> 4, cr = lane & 15;
  const int mbase = bx * 128 + wr * 64;
  const int nbase = by * 128 + wc * 64;
#pragma unroll
  for (int ni = 0; ni < 4; ++ni) {
    const int n = nbase + ni * 16 + cr;
    const float bias = bo[n];
#pragma unroll
    for (int mi = 0; mi < 4; ++mi) {
      const int mrow = mbase + mi * 16 + g * 4;
#pragma unroll
      for (int r = 0; r < 4; ++r)
        out[(size_t)(mrow + r) * 768 + n] = acc[mi][ni][r] + bias;
    }
  }
}

// ---------------------------------------------------------------- launch
extern "C" void kernel_launch(void* const* d_in, const int* in_sizes, int n_in,
                              void* d_out, int out_size, void* d_ws, size_t ws_size,
                              hipStream_t stream) {
  const float* x  = (const float*)d_in[0];
  const float* Wq = (const float*)d_in[1];
  const float* bq = (const float*)d_in[2];
  const float* Wk = (const float*)d_in[3];
  const float* bk = (const float*)d_in[4];
  const float* Wv = (const float*)d_in[5];
  const float* bv = (const float*)d_in[6];
  const float* Wo = (const float*)d_in[7];
  const float* bo = (const float*)d_in[8];
  float* out = (float*)d_out;

  char* ws = (char*)d_ws;
  u16* xb    = (u16*)(ws);                  // 16384x768 bf16      = 25165824 B
  u16* wqkvT = (u16*)(ws + 25165824);       // 2304x768            =  3538944 B
  u16* woT   = (u16*)(ws + 28704768);       // 768x768             =  1179648 B
  u16* qbuf  = (u16*)(ws + 29884416);       // [B,H,S,HD]          = 25165824 B
  u16* kbuf  = (u16*)(ws + 55050240);       // [B,H,S,HD]          = 25165824 B
  u16* vbuf  = (u16*)(ws + 80216064);       // [B,H,HD,S]          = 25165824 B
  u16* obuf  = (u16*)(ws + 105381888);      // [B,S,H*HD]          = 25165824 B
                                            // total 130547712 B

  k_convert_x<<<4096, 256, 0, stream>>>(x, xb);
  k_convert_w<<<9216, 256, 0, stream>>>(Wq, Wk, Wv, Wo, wqkvT, woT);
  k_gemm_qkv<<<2304, 256, 0, stream>>>(xb, wqkvT, bq, bk, bv,
                                       qbuf, kbuf, vbuf);
  attn<<<1536, 256, 0, stream>>>(qbuf, kbuf, vbuf, obuf);
  k_gemm_out<<<768, 256, 0, stream>>>(obuf, woT, bo, out);
}

// Round 12
// 362.769 us; speedup vs baseline: 1.0406x; 1.0177x over previous
//
#include <hip/hip_runtime.h>
#include <hip/hip_bf16.h>
#include <stdint.h>

// Problem constants: B=16, S=1024, D=768, H=12, HD=64
// log2(e)/sqrt(64) folded into stored q so softmax runs in exp2 domain.
#define QSCALE 0.1803368801111204f

typedef unsigned short u16;
typedef __attribute__((ext_vector_type(8))) short short8;   // 8 bf16 = 4 VGPR
typedef __attribute__((ext_vector_type(4))) float f32x4;    // MFMA 16x16 acc

__device__ __forceinline__ u16 f2bf(float f) {  // RNE f32->bf16
  uint32_t x = __builtin_bit_cast(uint32_t, f);
  x += 0x7fffu + ((x >> 16) & 1u);
  return (u16)(x >> 16);
}

__device__ __forceinline__ uint32_t cvtpk(float lo, float hi) {
  uint32_t r;
  asm("v_cvt_pk_bf16_f32 %0, %1, %2" : "=v"(r) : "v"(lo), "v"(hi));
  return r;
}

__device__ __forceinline__ void async16(const void* g, void* l) {
  __builtin_amdgcn_global_load_lds(
      (const __attribute__((address_space(1))) uint32_t*)g,
      (__attribute__((address_space(3))) uint32_t*)l, 16, 0, 0);
}

// ---------------------------------------------------------------- converts
__global__ void __launch_bounds__(256) k_convert_x(const float* __restrict__ x,
                                                   u16* __restrict__ xb) {
  const int n4 = (16 * 1024 * 768) / 4;
  int i = blockIdx.x * 256 + threadIdx.x;
  const int stride = gridDim.x * 256;
  for (; i < n4; i += stride) {
    float4 v = ((const float4*)x)[i];
    uint2 u;
    u.x = cvtpk(v.x, v.y);
    u.y = cvtpk(v.z, v.w);
    ((uint2*)xb)[i] = u;
  }
}

// wqkvT[n][d] = W{q,k,v}[d][n%768]  (n = proj*768 + h*64 + e), bf16
// woT[e][hhd] = Wo[hhd][e], bf16
__global__ void __launch_bounds__(256) k_convert_w(
    const float* __restrict__ Wq, const float* __restrict__ Wk,
    const float* __restrict__ Wv, const float* __restrict__ Wo,
    u16* __restrict__ wqkvT, u16* __restrict__ woT) {
  int idx = blockIdx.x * 256 + threadIdx.x;  // 9216*256 == 2359296 exact
  if (idx < 2304 * 768) {
    int nrow = idx / 768;
    int d = idx - nrow * 768;
    int proj = nrow / 768;
    int rem = nrow - proj * 768;
    const float* W = (proj == 0) ? Wq : ((proj == 1) ? Wk : Wv);
    wqkvT[idx] = f2bf(W[d * 768 + rem]);
  } else {
    int j = idx - 2304 * 768;
    int e = j / 768;
    int hhd = j - e * 768;
    woT[j] = f2bf(Wo[hhd * 768 + e]);
  }
}

// ---------------------------------------------------------------- GEMM core
// ROUND-7 MEASURED-BEST core (124 us qkv): single-buffered m97 structure,
// 128x128 tile, BK=32, 4 waves 2x2, global_load_lds width16, two barriers
// per K-step. Both "improvements" measured WORSE on this K=768 shape:
// 2-phase dbuf = 136 us (r8), counted-vmcnt = 153 us (r11) — the m97
// ceiling story (m131-m141). Do not re-add source-level pipelining here;
// the only proven path up is the full 8-phase 256^2 template.
__device__ __forceinline__ void gemm_tile_k768(const u16* __restrict__ Atile,
                                               const u16* __restrict__ Btile,
                                               u16* As, u16* Bs,
                                               f32x4 acc[4][4]) {
  const int tid = threadIdx.x;
  const int lane = tid & 63, w = tid >> 6;
  const int wr = w >> 1, wc = w & 1;
  const int g = lane >> 4, cr = lane & 15;
  const int q0 = tid, q1 = tid + 256;
  const size_t ga0 = (size_t)(q0 >> 2) * 1536 + (size_t)((q0 & 3) * 16);
  const size_t ga1 = (size_t)(q1 >> 2) * 1536 + (size_t)((q1 & 3) * 16);

  for (int kt = 0; kt < 24; ++kt) {
    const char* Ag = (const char*)Atile + kt * 64;
    const char* Bg = (const char*)Btile + kt * 64;
    async16(Ag + ga0, (char*)As + q0 * 16);
    async16(Ag + ga1, (char*)As + q1 * 16);
    async16(Bg + ga0, (char*)Bs + q0 * 16);
    async16(Bg + ga1, (char*)Bs + q1 * 16);
    __syncthreads();  // drains vmcnt for global_load_lds
    short8 a[4], b[4];
#pragma unroll
    for (int i = 0; i < 4; ++i)
      a[i] = *(const short8*)(As + (wr * 64 + i * 16 + cr) * 32 + g * 8);
#pragma unroll
    for (int i = 0; i < 4; ++i)
      b[i] = *(const short8*)(Bs + (wc * 64 + i * 16 + cr) * 32 + g * 8);
#pragma unroll
    for (int mi = 0; mi < 4; ++mi)
#pragma unroll
      for (int ni = 0; ni < 4; ++ni)
        acc[mi][ni] = __builtin_amdgcn_mfma_f32_16x16x32_bf16(
            a[mi], b[ni], acc[mi][ni], 0, 0, 0);
    __syncthreads();
  }
}

// ------------------------------------------------------------- GEMM1: QKV
// 1-D grid 2304 = 8 XCD chunks x 288; within chunk y-minor (by = lb%18) so
// the 3.5MB weight set stays L2-resident and each A-panel is reused 18x.
__global__ void __launch_bounds__(256) k_gemm_qkv(
    const u16* __restrict__ xb, const u16* __restrict__ wT,
    const float* __restrict__ bq, const float* __restrict__ bk,
    const float* __restrict__ bv,
    u16* __restrict__ qbuf, u16* __restrict__ kbuf, u16* __restrict__ vbuf) {
  __shared__ __align__(16) u16 As[128 * 32];
  __shared__ __align__(16) u16 Bs[128 * 32];
  const int lb = (blockIdx.x & 7) * 288 + (blockIdx.x >> 3);
  const int bx = lb / 18, by = lb - bx * 18;

  f32x4 acc[4][4];
#pragma unroll
  for (int i = 0; i < 4; ++i)
#pragma unroll
    for (int j = 0; j < 4; ++j) acc[i][j] = (f32x4){0.f, 0.f, 0.f, 0.f};

  gemm_tile_k768(xb + (size_t)bx * 128 * 768,
                 wT + (size_t)by * 128 * 768, As, Bs, acc);

  const int lane = threadIdx.x & 63, w = threadIdx.x >> 6;
  const int wr = w >> 1, wc = w & 1, g = lane >> 4, cr = lane & 15;
  const int mbase = bx * 128 + wr * 64;
  const int nbase = by * 128 + wc * 64;
#pragma unroll
  for (int ni = 0; ni < 4; ++ni) {
    const int n = nbase + ni * 16 + cr;
    const int proj = n / 768;           // fragment never straddles (768%16==0)
    const int rem = n - proj * 768;     // h*64+e
    const int h = rem >> 6, e = rem & 63;
    const float bias = ((proj == 0) ? bq : (proj == 1) ? bk : bv)[rem];
#pragma unroll
    for (int mi = 0; mi < 4; ++mi) {
      const int mrow = mbase + mi * 16 + g * 4;
      const int b = mrow >> 10, s0 = mrow & 1023;
#pragma unroll
      for (int r = 0; r < 4; ++r) {
        const float val = acc[mi][ni][r] + bias;
        const int s = s0 + r;
        if (proj == 0) {
          qbuf[((size_t)(b * 12 + h) * 1024 + s) * 64 + e] = f2bf(val * QSCALE);
        } else if (proj == 1) {
          kbuf[((size_t)(b * 12 + h) * 1024 + s) * 64 + e] = f2bf(val);
        } else {
          vbuf[((size_t)(b * 12 + h) * 64 + e) * 1024 + s] = f2bf(val);
        }
      }
    }
  }
}

// --------------------------------------------------------------- attention
// NEW: 1 block = (b,h, 256 q rows); 8 waves x 32 q-rows, 512 threads.
// Halves K/V re-reads (4 q-blocks per (b,h) instead of 8) and raises
// waves/CU 12 -> 16 (LDS 64KB -> 2 blocks/CU). Per-wave math unchanged.
// Swapped QK^T (S^T = mfma(K,Q)); T13 defer-max; cvt_pk P-pack; XOR-swizzled
// K/V tiles staged via pre-swizzled global source (rule #21).
__global__ void __launch_bounds__(512) attn(const u16* __restrict__ qb,
                                            const u16* __restrict__ kb,
                                            const u16* __restrict__ vb,
                                            u16* __restrict__ ob) {
  __shared__ __align__(16) u16 Ks[2][64 * 64];
  __shared__ __align__(16) u16 Vs[2][64 * 64];
  __shared__ __align__(16) u16 Ps[8][32 * 64];  // per-wave P scratch

  // T1 chunked swizzle: 768 blocks = 8 XCDs x 96; 96 = 24 (b,h) x 4 q-tiles.
  const int lb = (blockIdx.x & 7) * 96 + (blockIdx.x >> 3);
  const int bh = lb >> 2, qi = lb & 3;
  const int tid = threadIdx.x, lane = tid & 63, w = tid >> 6;
  const int g = lane >> 4, cr = lane & 15;

  const u16* qbase = qb + ((size_t)bh * 1024 + qi * 256 + w * 32) * 64;
  const char* kbase = (const char*)(kb + (size_t)bh * 1024 * 64);
  const char* vbase = (const char*)(vb + (size_t)bh * 1024 * 64);

  // Q fragments in registers (pre-scaled by log2e/8 at projection time)
  short8 qf[2][2];
#pragma unroll
  for (int m = 0; m < 2; ++m)
#pragma unroll
    for (int kk = 0; kk < 2; ++kk)
      qf[m][kk] = *(const short8*)(qbase + (m * 16 + cr) * 64 + kk * 32 + g * 8);

  f32x4 O[2][4];
  float mrun[2], lrun[2];
#pragma unroll
  for (int m = 0; m < 2; ++m) {
#pragma unroll
    for (int i = 0; i < 4; ++i) O[m][i] = (f32x4){0.f, 0.f, 0.f, 0.f};
    mrun[m] = -1e30f;
    lrun[m] = 0.f;
  }

  // staging: 512 threads x 16B = one 64x64 bf16 tile per buffer
  const int r0 = tid >> 3;                       // tile row 0..63
  const int sc0 = ((tid & 7) * 16) ^ ((r0 & 7) << 4);  // pre-swizzled col
  char* Psw = (char*)&Ps[w][0];

#define STAGE(buf, t)                                                        \
  do {                                                                       \
    async16(kbase + (size_t)((t)*64 + r0) * 128 + sc0, (char*)Ks[buf] + tid * 16); \
    async16(vbase + (size_t)r0 * 2048 + (t)*128 + sc0, (char*)Vs[buf] + tid * 16); \
  } while (0)

  STAGE(0, 0);
  __syncthreads();  // drain prologue loads
  int cur = 0;

  for (int t = 0; t < 16; ++t) {
    if (t < 15) STAGE(cur ^ 1, t + 1);  // issue next tile early (hides HBM)

    // ---- S^T = K * Q^T : C[row=kv_local][col=q_local]
    short8 kf[4][2];
#pragma unroll
    for (int n = 0; n < 4; ++n)
#pragma unroll
      for (int kk = 0; kk < 2; ++kk) {
        const int row = n * 16 + cr;
        kf[n][kk] = *(const short8*)((char*)Ks[cur] + row * 128 +
                                     ((kk * 64 + g * 16) ^ ((row & 7) << 4)));
      }
    f32x4 sT[4][2];  // [kv-frag n][q-half m]
#pragma unroll
    for (int n = 0; n < 4; ++n)
#pragma unroll
      for (int m = 0; m < 2; ++m) sT[n][m] = (f32x4){0.f, 0.f, 0.f, 0.f};
    __builtin_amdgcn_s_setprio(1);
#pragma unroll
    for (int n = 0; n < 4; ++n)
#pragma unroll
      for (int kk = 0; kk < 2; ++kk) {
        sT[n][0] = __builtin_amdgcn_mfma_f32_16x16x32_bf16(kf[n][kk], qf[0][kk], sT[n][0], 0, 0, 0);
        sT[n][1] = __builtin_amdgcn_mfma_f32_16x16x32_bf16(kf[n][kk], qf[1][kk], sT[n][1], 0, 0, 0);
      }
    __builtin_amdgcn_s_setprio(0);

    // ---- tile max per q-column (tree shape -> v_max3 fusable)
    float mx[2];
#pragma unroll
    for (int m = 0; m < 2; ++m) {
      float t0 = fmaxf(fmaxf(sT[0][m][0], sT[0][m][1]), fmaxf(sT[0][m][2], sT[0][m][3]));
      float t1 = fmaxf(fmaxf(sT[1][m][0], sT[1][m][1]), fmaxf(sT[1][m][2], sT[1][m][3]));
      float t2 = fmaxf(fmaxf(sT[2][m][0], sT[2][m][1]), fmaxf(sT[2][m][2], sT[2][m][3]));
      float t3 = fmaxf(fmaxf(sT[3][m][0], sT[3][m][1]), fmaxf(sT[3][m][2], sT[3][m][3]));
      float v = fmaxf(fmaxf(t0, t1), fmaxf(t2, t3));
      v = fmaxf(v, __shfl_xor(v, 16));
      v = fmaxf(v, __shfl_xor(v, 32));
      mx[m] = v;
    }

    // ---- T13 defer-max: rescale only when some column grew by > 8
    if (!__all(mx[0] <= mrun[0] + 8.f && mx[1] <= mrun[1] + 8.f)) {
      float al[2];
#pragma unroll
      for (int m = 0; m < 2; ++m) {
        const float mnew = fmaxf(mrun[m], mx[m]);
        al[m] = __builtin_amdgcn_exp2f(mrun[m] - mnew);
        mrun[m] = mnew;
        lrun[m] *= al[m];
      }
#pragma unroll
      for (int m = 0; m < 2; ++m)
#pragma unroll
        for (int r = 0; r < 4; ++r) {
          const float aO = __shfl(al[m], (g << 4) + g * 4 + r, 64);
#pragma unroll
          for (int nn = 0; nn < 4; ++nn) O[m][nn][r] *= aO;
        }
    }

    // ---- P = exp2(S - m), row-sum, pack to bf16, write b64 to Ps
#pragma unroll
    for (int m = 0; m < 2; ++m) {
      const float mm = mrun[m];
      float rs = 0.f;
      const int q = m * 16 + cr;
      const int swz = (q & 7) << 4;
      char* prow = Psw + q * 128;
#pragma unroll
      for (int n = 0; n < 4; ++n) {
        float p0 = __builtin_amdgcn_exp2f(sT[n][m][0] - mm);
        float p1 = __builtin_amdgcn_exp2f(sT[n][m][1] - mm);
        float p2 = __builtin_amdgcn_exp2f(sT[n][m][2] - mm);
        float p3 = __builtin_amdgcn_exp2f(sT[n][m][3] - mm);
        rs += (p0 + p1) + (p2 + p3);
        uint2 pw;
        pw.x = cvtpk(p0, p1);
        pw.y = cvtpk(p2, p3);
        *(uint2*)(prow + ((n * 32 + g * 8) ^ swz)) = pw;
      }
      rs += __shfl_xor(rs, 16);
      rs += __shfl_xor(rs, 32);
      lrun[m] += rs;
    }

    // ---- O += P * V : A=P (rows=q), B=V (cols=hd) -> C[row=q][col=hd]
    short8 pf[2][2];
#pragma unroll
    for (int m = 0; m < 2; ++m)
#pragma unroll
      for (int kk = 0; kk < 2; ++kk) {
        const int q = m * 16 + cr;
        pf[m][kk] = *(const short8*)(Psw + q * 128 +
                                     ((kk * 64 + g * 16) ^ ((q & 7) << 4)));
      }
    short8 vf[4][2];
#pragma unroll
    for (int nn = 0; nn < 4; ++nn)
#pragma unroll
      for (int kk = 0; kk < 2; ++kk) {
        const int row = nn * 16 + cr;
        vf[nn][kk] = *(const short8*)((char*)Vs[cur] + row * 128 +
                                      ((kk * 64 + g * 16) ^ ((row & 7) << 4)));
      }
    __builtin_amdgcn_s_setprio(1);
#pragma unroll
    for (int nn = 0; nn < 4; ++nn)
#pragma unroll
      for (int kk = 0; kk < 2; ++kk) {
        O[0][nn] = __builtin_amdgcn_mfma_f32_16x16x32_bf16(pf[0][kk], vf[nn][kk], O[0][nn], 0, 0, 0);
        O[1][nn] = __builtin_amdgcn_mfma_f32_16x16x32_bf16(pf[1][kk], vf[nn][kk], O[1][nn], 0, 0, 0);
      }
    __builtin_amdgcn_s_setprio(0);

    __syncthreads();  // drain next-tile loads + protect Ks/Vs reuse
    cur ^= 1;
  }
#undef STAGE

  // epilogue: o[b][s][h*64+hd] bf16; row q = m*16+g*4+r, col hd = nn*16+cr
  const int b = bh / 12, h = bh - b * 12;
#pragma unroll
  for (int m = 0; m < 2; ++m)
#pragma unroll
    for (int r = 0; r < 4; ++r) {
      const float l = __shfl(lrun[m], (g << 4) + g * 4 + r, 64);
      const float inv = 1.0f / l;
      const int s = qi * 256 + w * 32 + m * 16 + g * 4 + r;
      const size_t rowoff = (size_t)(b * 1024 + s) * 768 + h * 64;
#pragma unroll
      for (int nn = 0; nn < 4; ++nn)
        ob[rowoff + nn * 16 + cr] = f2bf(O[m][nn][r] * inv);
    }
}

// ------------------------------------------------------------ GEMM2: out
// 1-D grid 768 = 8 XCD chunks x 96; y-minor (by = lb%6).
__global__ void __launch_bounds__(256) k_gemm_out(
    const u16* __restrict__ obuf, const u16* __restrict__ woT,
    const float* __restrict__ bo, float* __restrict__ out) {
  __shared__ __align__(16) u16 As[128 * 32];
  __shared__ __align__(16) u16 Bs[128 * 32];
  const int lb = (blockIdx.x & 7) * 96 + (blockIdx.x >> 3);
  const int bx = lb / 6, by = lb - bx * 6;

  f32x4 acc[4][4];
#pragma unroll
  for (int i = 0; i < 4; ++i)
#pragma unroll
    for (int j = 0; j < 4; ++j) acc[i][j] = (f32x4){0.f, 0.f, 0.f, 0.f};

  gemm_tile_k768(obuf + (size_t)bx * 128 * 768,
                 woT + (size_t)by * 128 * 768, As, Bs, acc);

  const int lane = threadIdx.x & 63, w = threadIdx.x >> 6;
  const int wr = w >> 1, wc = w & 1, g = lane >> 4, cr = lane & 15;
  const int mbase = bx * 128 + wr * 64;
  const int nbase = by * 128 + wc * 64;
#pragma unroll
  for (int ni = 0; ni < 4; ++ni) {
    const int n = nbase + ni * 16 + cr;
    const float bias = bo[n];
#pragma unroll
    for (int mi = 0; mi < 4; ++mi) {
      const int mrow = mbase + mi * 16 + g * 4;
#pragma unroll
      for (int r = 0; r < 4; ++r)
        out[(size_t)(mrow + r) * 768 + n] = acc[mi][ni][r] + bias;
    }
  }
}

// ---------------------------------------------------------------- launch
extern "C" void kernel_launch(void* const* d_in, const int* in_sizes, int n_in,
                              void* d_out, int out_size, void* d_ws, size_t ws_size,
                              hipStream_t stream) {
  const float* x  = (const float*)d_in[0];
  const float* Wq = (const float*)d_in[1];
  const float* bq = (const float*)d_in[2];
  const float* Wk = (const float*)d_in[3];
  const float* bk = (const float*)d_in[4];
  const float* Wv = (const float*)d_in[5];
  const float* bv = (const float*)d_in[6];
  const float* Wo = (const float*)d_in[7];
  const float* bo = (const float*)d_in[8];
  float* out = (float*)d_out;

  char* ws = (char*)d_ws;
  u16* xb    = (u16*)(ws);                  // 16384x768 bf16      = 25165824 B
  u16* wqkvT = (u16*)(ws + 25165824);       // 2304x768            =  3538944 B
  u16* woT   = (u16*)(ws + 28704768);       // 768x768             =  1179648 B
  u16* qbuf  = (u16*)(ws + 29884416);       // [B,H,S,HD]          = 25165824 B
  u16* kbuf  = (u16*)(ws + 55050240);       // [B,H,S,HD]          = 25165824 B
  u16* vbuf  = (u16*)(ws + 80216064);       // [B,H,HD,S]          = 25165824 B
  u16* obuf  = (u16*)(ws + 105381888);      // [B,S,H*HD]          = 25165824 B
                                            // total 130547712 B

  k_convert_x<<<4096, 256, 0, stream>>>(x, xb);
  k_convert_w<<<9216, 256, 0, stream>>>(Wq, Wk, Wv, Wo, wqkvT, woT);
  k_gemm_qkv<<<2304, 256, 0, stream>>>(xb, wqkvT, bq, bk, bv,
                                       qbuf, kbuf, vbuf);
  attn<<<768, 512, 0, stream>>>(qbuf, kbuf, vbuf, obuf);
  k_gemm_out<<<768, 256, 0, stream>>>(obuf, woT, bo, out);
}